// Round 21
// baseline (90.504 us; speedup 1.0000x reference)
//
#include <hip/hip_runtime.h>
#include <stdint.h>

#define NN 15000
#define NE 60000

typedef unsigned short u16;
typedef __attribute__((ext_vector_type(8))) short short8;
typedef __attribute__((ext_vector_type(4))) float f32x4;

// workspace layout (bytes)
#define XF_OFF    0u          // xf   : 15000*64*2 = 1,920,000
#define W2T_OFF   1920000u    // w2t  : 65*4096*2  =   532,480
#define ROOTT_OFF 2452480u    // rootT: 64*64*2    =     8,192
#define WCATT_OFF 2460672u    // wcatT: 240*64*2   =    30,720
#define SUMS_OFF  2491392u    // sums+cnt: 15000*65*4 = 3,900,000
#define H2_OFF    6391392u    // h2   : [e/4][64][4] = 60000*64*2 = 7,680,000 -> end 14,071,392

__device__ __forceinline__ unsigned cvtpk(float lo, float hi) {
    unsigned r;
    asm("v_cvt_pk_bf16_f32 %0, %1, %2" : "=v"(r) : "v"(lo), "v"(hi));
    return r;
}
__device__ __forceinline__ u16 f2b(float f) { return (u16)(cvtpk(f, f) & 0xffffu); }

// =============== K1: fused {h-MLP(MFMA)->h2, xf, weight-prep, zero} ===============
// block ranges: [0,235) h (16 edge-groups/block) | [235,1173) xf | [1173,2289) prep | [2289,3242) zero
__global__ __launch_bounds__(256) void k_pre(
        const float* __restrict__ x,
        const int* __restrict__ inp, const int* __restrict__ outp,
        const int* __restrict__ ent, const int* __restrict__ enp,
        const float* __restrict__ esc,
        const float* __restrict__ in_emb, const float* __restrict__ out_emb,
        const float* __restrict__ nt_emb, const float* __restrict__ np_emb,
        const float* __restrict__ w1, const float* __restrict__ b1,
        const float* __restrict__ w2, const float* __restrict__ b2,
        const float* __restrict__ rootw,
        const float* __restrict__ wsup, const float* __restrict__ wnt,
        const float* __restrict__ wtg, const float* __restrict__ wpr,
        u16* __restrict__ xf, u16* __restrict__ w2t,
        u16* __restrict__ rootT, u16* __restrict__ wcatT,
        u16* __restrict__ h2, float4* __restrict__ zbase) {
    const int bid = blockIdx.x, tid = threadIdx.x;
    if (bid < 235) {
        // ---- h = relu(ea @ w1 + b1) via MFMA; output in h2 stream layout
        // h2[(e>>2)*256 + k*4 + (e&3)].
        __shared__ __align__(16) u16 w1t[64 * 64];   // [col][k], k 33..63 zero-padded
        __shared__ float b1s[64];
        const int lane = tid & 63, wave = tid >> 6;
        const int lhi = lane >> 4, llo = lane & 15;
        for (int idx = tid; idx < 4096; idx += 256) {
            int col = idx >> 6, k = idx & 63;
            w1t[col * 64 + k] = f2b((k < 33) ? w1[k * 64 + col] : 0.f);
        }
        if (tid < 64) b1s[tid] = b1[tid];
        __syncthreads();
        #pragma unroll 1
        for (int it = 0; it < 4; ++it) {
            int g = bid * 16 + wave * 4 + it;       // 16-edge group
            if (g >= 3750) break;                   // 60000/16 = 3750 exactly
            int e = g * 16 + llo;                   // A-frag row = edge
            short8 A0;
            {
                const float* src = (lhi < 2) ? (nt_emb + (size_t)ent[e] * 16 + lhi * 8)
                                             : (np_emb + (size_t)enp[e] * 16 + (lhi - 2) * 8);
                float4 v0 = *(const float4*)(src);
                float4 v1 = *(const float4*)(src + 4);
                union { short8 s; unsigned u[4]; } Au;
                Au.u[0] = cvtpk(v0.x, v0.y); Au.u[1] = cvtpk(v0.z, v0.w);
                Au.u[2] = cvtpk(v1.x, v1.y); Au.u[3] = cvtpk(v1.z, v1.w);
                A0 = Au.s;
            }
            short8 A1 = (short8){0, 0, 0, 0, 0, 0, 0, 0};
            if (lhi == 0) {
                union { short8 s; unsigned u[4]; } Au;
                Au.s = A1; Au.u[0] = cvtpk(esc[e], 0.f); A1 = Au.s;
            }
            #pragma unroll
            for (int o = 0; o < 4; ++o) {
                short8 B0 = *(const short8*)(&w1t[(o * 16 + llo) * 64 + lhi * 8]);
                short8 B1 = *(const short8*)(&w1t[(o * 16 + llo) * 64 + 32 + lhi * 8]);
                f32x4 q;
                q = __builtin_amdgcn_mfma_f32_16x16x32_bf16(A0, B0, (f32x4){0.f,0.f,0.f,0.f}, 0, 0, 0);
                q = __builtin_amdgcn_mfma_f32_16x16x32_bf16(A1, B1, q, 0, 0, 0);
                int kh = o * 16 + llo;              // hidden unit (D col)
                float bv = b1s[kh];
                float v0 = fmaxf(q[0] + bv, 0.f), v1 = fmaxf(q[1] + bv, 0.f);
                float v2 = fmaxf(q[2] + bv, 0.f), v3 = fmaxf(q[3] + bv, 0.f);
                uint2 pk2 = make_uint2(cvtpk(v0, v1), cvtpk(v2, v3));
                *(uint2*)(h2 + (size_t)(g * 4 + lhi) * 256 + kh * 4) = pk2;
            }
        }
    } else if (bid < 1173) {
        // ---- xf = bf16(concat(x, in_emb[inp], out_emb[outp])) ----
        int t = (bid - 235) * 256 + tid;
        if (t >= NN * 16) return;
        int n = t >> 4, j4 = t & 15;
        float4 v;
        if (j4 < 8)       v = *(const float4*)(x + n * 32 + j4 * 4);
        else if (j4 < 12) v = *(const float4*)(in_emb + inp[n] * 16 + (j4 - 8) * 4);
        else              v = *(const float4*)(out_emb + outp[n] * 16 + (j4 - 12) * 4);
        uint2 p;
        p.x = cvtpk(v.x, v.y);
        p.y = cvtpk(v.z, v.w);
        *(uint2*)(xf + n * 64 + j4 * 4) = p;
    } else if (bid < 2289) {
        // ---- weight re-layouts ----
        int idx = (bid - 1173) * 256 + tid;
        if (idx < 65 * 4096) {
            int k = idx >> 12, r = idx & 4095, o = r >> 6, i = r & 63;
            float v = (k < 64) ? w2[(k << 12) + (i << 6) + o] : b2[(i << 6) + o];
            w2t[idx] = f2b(v);
        } else if (idx < 65 * 4096 + 4096) {
            int t = idx - 65 * 4096; int c = t >> 6, i = t & 63;
            rootT[t] = f2b(rootw[i * 64 + c]);
        } else if (idx < 65 * 4096 + 4096 + 15360) {
            int t = idx - (65 * 4096 + 4096); int col = t >> 6, k = t & 63;
            float v;
            if (col < 16)       v = wsup[k * 16 + col];
            else if (col < 48)  v = wnt[k * 32 + col - 16];
            else if (col < 112) v = wtg[k * 64 + col - 48];
            else                v = wpr[k * 128 + col - 112];
            wcatT[t] = f2b(v);
        }
    } else {
        // ---- zero sums+cnt ----
        int i = (bid - 2289) * 256 + tid;
        if (i < (NN * 65) / 4) zbase[i] = make_float4(0.f, 0.f, 0.f, 0.f);
    }
}

// =============== K2: fused msg GEMM + scatter-add (o+k partitioned, 2 blocks/CU) ===============
// msg[e,o] = sum_k h[e,k]*q_k[e,o] + bias,  q_k[e,o] = sum_i g[e,i]*w2t[k][o][i]
// ROUND-21: the round-19 plateau (48.6us vs ~23us LDS floor, nothing saturated) is pure
// dependent-chain latency at 4 waves/SIMD; register levers exhausted (cap 64, state 52).
// The occupancy lever: 130KB LDS pinned 1 block/CU. SPLIT k in half per block:
// grid 512 = 4 oq x 2 ks x 64 chunks; block = 1024 thr, 33x2KB = 66KB LDS -> 2 blocks/CU
// -> 8 waves/SIMD. Costs (measured-safe): atomics x2 (~35.6MB), a-gathers x2 (+9MB FETCH).
// XCD locality preserved: xcd=bid&7 picks the chunk range -> ~1MB h2 per XCD, L2-resident.
// setprio REMOVED (round-20: null-to-negative). Loop body = round-19's proven 52-reg version.
__global__ __launch_bounds__(1024)
void k_msg(const int* __restrict__ ei,
           const u16* __restrict__ xf,
           const u16* __restrict__ h2,
           const u16* __restrict__ w2t,
           float* __restrict__ sums,
           float* __restrict__ cnt) {
    __shared__ __align__(16) char smem[33 * 2048];   // 67,584 B
    const int tid  = threadIdx.x;
    const int lane = tid & 63;
    const int wave = tid >> 6;                       // 0..15
    const int lhi  = lane >> 4;
    const int llo  = lane & 15;
    const int bid  = blockIdx.x;
    const int xcd  = bid & 7;
    const int j    = bid >> 3;                       // 0..63
    const int oq   = j & 3;                          // 16-col quarter
    const int ks   = (j >> 2) & 1;                   // k-half
    const int kb   = ks * 32;
    const int chunk = xcd * 8 + (j >> 3);            // 0..63 (XCD-local h2 range)
    const int wslot = chunk * 16 + wave;             // 0..1023 per (oq,ks)
    const int ns   = (ks == 0) ? 33 : 32;            // ks=0 also holds the bias slice

    // ---- one-time LDS fill: this (oq,ks)'s 2KB portion of each slice ----
    for (int sl = wave; sl < ns; sl += 16) {
        int gsl = (sl == 32) ? 64 : kb + sl;
        const char* src = (const char*)w2t + (size_t)gsl * 8192 + oq * 2048;
        char* dst = smem + sl * 2048;
        #pragma unroll
        for (int it = 0; it < 2; ++it) {
            int lin = (lane + it * 64) * 16;
            int phys = lin ^ (((lin >> 7) & 7) << 4);
            *(uint4*)(dst + phys) = *(const uint4*)(src + lin);
        }
    }
    __syncthreads();   // only barrier in the kernel

    const int pc0 = (llo * 128 + lhi * 16) ^ ((llo & 7) << 4);
    const int pc1 = (llo * 128 + 64 + lhi * 16) ^ ((llo & 7) << 4);

    for (int t = wslot; t < 1875; t += 1024) {       // 32-edge tiles; 1875*32 = 60000 exactly
        const int base = t * 32;
        short8 a[2][2]; int eb[2];
        #pragma unroll
        for (int st = 0; st < 2; ++st) {
            int e = base + st * 16 + llo;
            int src = ei[e];
            a[st][0] = *(const short8*)(xf + (size_t)src * 64 + lhi * 8);
            a[st][1] = *(const short8*)(xf + (size_t)src * 64 + 32 + lhi * 8);
            eb[st] = base + st * 16 + lhi * 4;
        }
        f32x4 acc[2];
        acc[0] = (f32x4){0.f, 0.f, 0.f, 0.f};
        acc[1] = (f32x4){0.f, 0.f, 0.f, 0.f};

        #pragma unroll 1   // CRITICAL: full unroll caused the round-9/10 spill storm
        for (int s = 0; s < 32; s += 2) {
            // h chunk: uint4 = slices {kb+s, kb+s+1} x this lane's 4 edges (L2-resident)
            uint4 hc0 = *(const uint4*)(h2 + ((size_t)(eb[0] >> 2) << 8) + (kb + s) * 4);
            uint4 hc1 = *(const uint4*)(h2 + ((size_t)(eb[1] >> 2) << 8) + (kb + s) * 4);
            {   // slice s (h in hc*.x/.y)
                const char* bb = smem + s * 2048;
                short8 B0 = *(const short8*)(bb + pc0);
                short8 B1 = *(const short8*)(bb + pc1);
                f32x4 q0, q1;
                q0 = __builtin_amdgcn_mfma_f32_16x16x32_bf16(a[0][0], B0, (f32x4){0.f,0.f,0.f,0.f}, 0, 0, 0);
                q0 = __builtin_amdgcn_mfma_f32_16x16x32_bf16(a[0][1], B1, q0, 0, 0, 0);
                q1 = __builtin_amdgcn_mfma_f32_16x16x32_bf16(a[1][0], B0, (f32x4){0.f,0.f,0.f,0.f}, 0, 0, 0);
                q1 = __builtin_amdgcn_mfma_f32_16x16x32_bf16(a[1][1], B1, q1, 0, 0, 0);
                union { unsigned u; float f; } u0, u1, u2, u3;
                u0.u = hc0.x << 16;         u1.u = hc0.x & 0xffff0000u;
                u2.u = hc0.y << 16;         u3.u = hc0.y & 0xffff0000u;
                acc[0][0] = fmaf(u0.f, q0[0], acc[0][0]);
                acc[0][1] = fmaf(u1.f, q0[1], acc[0][1]);
                acc[0][2] = fmaf(u2.f, q0[2], acc[0][2]);
                acc[0][3] = fmaf(u3.f, q0[3], acc[0][3]);
                u0.u = hc1.x << 16;         u1.u = hc1.x & 0xffff0000u;
                u2.u = hc1.y << 16;         u3.u = hc1.y & 0xffff0000u;
                acc[1][0] = fmaf(u0.f, q1[0], acc[1][0]);
                acc[1][1] = fmaf(u1.f, q1[1], acc[1][1]);
                acc[1][2] = fmaf(u2.f, q1[2], acc[1][2]);
                acc[1][3] = fmaf(u3.f, q1[3], acc[1][3]);
            }
            {   // slice s+1 (h in hc*.z/.w)
                const char* bb = smem + (s + 1) * 2048;
                short8 B0 = *(const short8*)(bb + pc0);
                short8 B1 = *(const short8*)(bb + pc1);
                f32x4 q0, q1;
                q0 = __builtin_amdgcn_mfma_f32_16x16x32_bf16(a[0][0], B0, (f32x4){0.f,0.f,0.f,0.f}, 0, 0, 0);
                q0 = __builtin_amdgcn_mfma_f32_16x16x32_bf16(a[0][1], B1, q0, 0, 0, 0);
                q1 = __builtin_amdgcn_mfma_f32_16x16x32_bf16(a[1][0], B0, (f32x4){0.f,0.f,0.f,0.f}, 0, 0, 0);
                q1 = __builtin_amdgcn_mfma_f32_16x16x32_bf16(a[1][1], B1, q1, 0, 0, 0);
                union { unsigned u; float f; } u0, u1, u2, u3;
                u0.u = hc0.z << 16;         u1.u = hc0.z & 0xffff0000u;
                u2.u = hc0.w << 16;         u3.u = hc0.w & 0xffff0000u;
                acc[0][0] = fmaf(u0.f, q0[0], acc[0][0]);
                acc[0][1] = fmaf(u1.f, q0[1], acc[0][1]);
                acc[0][2] = fmaf(u2.f, q0[2], acc[0][2]);
                acc[0][3] = fmaf(u3.f, q0[3], acc[0][3]);
                u0.u = hc1.z << 16;         u1.u = hc1.z & 0xffff0000u;
                u2.u = hc1.w << 16;         u3.u = hc1.w & 0xffff0000u;
                acc[1][0] = fmaf(u0.f, q1[0], acc[1][0]);
                acc[1][1] = fmaf(u1.f, q1[1], acc[1][1]);
                acc[1][2] = fmaf(u2.f, q1[2], acc[1][2]);
                acc[1][3] = fmaf(u3.f, q1[3], acc[1][3]);
            }
        }
        if (ks == 0) {   // bias slice (LDS idx 32, h==1): MFMA straight into acc
            const char* bb = smem + 32 * 2048;
            short8 B0 = *(const short8*)(bb + pc0);
            short8 B1 = *(const short8*)(bb + pc1);
            #pragma unroll
            for (int st = 0; st < 2; ++st) {
                acc[st] = __builtin_amdgcn_mfma_f32_16x16x32_bf16(a[st][0], B0, acc[st], 0, 0, 0);
                acc[st] = __builtin_amdgcn_mfma_f32_16x16x32_bf16(a[st][1], B1, acc[st], 0, 0, 0);
            }
        }
        // scatter-add k-partial (C/D layout: col = oq*16+llo, row = lhi*4+r).
        #pragma unroll
        for (int st = 0; st < 2; ++st) {
            int4 d4 = *(const int4*)(ei + NE + eb[st]);
            #pragma unroll
            for (int r = 0; r < 4; ++r) {
                int d = (r == 0) ? d4.x : (r == 1) ? d4.y : (r == 2) ? d4.z : d4.w;
                atomicAdd(sums + (size_t)d * 64 + oq * 16 + llo, acc[st][r]);
                if (oq == 0 && ks == 0 && llo == 0) atomicAdd(cnt + d, 1.0f);
            }
        }
    }
}

// =============== K3: out = relu(aggr + xf@rootw + b); 4 heads (f32 out) ===============
__global__ __launch_bounds__(256) void k_out(const u16* __restrict__ xf,
                                             const float* __restrict__ sums,
                                             const float* __restrict__ cnt,
                                             const u16* __restrict__ rootT,
                                             const u16* __restrict__ wcatT,
                                             const float* __restrict__ convb,
                                             const float* __restrict__ bsup,
                                             const float* __restrict__ bnt,
                                             const float* __restrict__ btg,
                                             const float* __restrict__ bpr,
                                             float* __restrict__ outp) {
    __shared__ __align__(16) u16 outlds[4][16][72];
    int tid = threadIdx.x;
    int wave = tid >> 6, lane = tid & 63;
    int lhi = lane >> 4, llo = lane & 15;
    int sid = blockIdx.x * 4 + wave;
    const bool live = (sid < 938);
    if (!live) sid = 937;
    int n0 = sid * 16;

    short8 a1[2];
    #pragma unroll
    for (int c = 0; c < 2; ++c) {
        int node = n0 + llo; if (node >= NN) node = NN - 1;
        a1[c] = *(const short8*)(xf + (size_t)node * 64 + c * 32 + lhi * 8);
    }
    f32x4 racc[4];
    #pragma unroll
    for (int o = 0; o < 4; ++o) racc[o] = (f32x4){0.f, 0.f, 0.f, 0.f};
    #pragma unroll
    for (int c = 0; c < 2; ++c)
        #pragma unroll
        for (int o = 0; o < 4; ++o) {
            short8 b = *(const short8*)(rootT + (o * 16 + llo) * 64 + c * 32 + lhi * 8);
            racc[o] = __builtin_amdgcn_mfma_f32_16x16x32_bf16(a1[c], b, racc[o], 0, 0, 0);
        }
    #pragma unroll
    for (int o = 0; o < 4; ++o) {
        int col = o * 16 + llo;
        #pragma unroll
        for (int r = 0; r < 4; ++r) {
            int node = n0 + lhi * 4 + r;
            float v = 0.f;
            if (node < NN) v = sums[(size_t)node * 64 + col] / fmaxf(cnt[node], 1.0f);
            v += racc[o][r] + convb[col];
            v = fmaxf(v, 0.f);
            outlds[wave][lhi * 4 + r][col] = f2b(v);
        }
    }
    __syncthreads();
    short8 a2[2];
    #pragma unroll
    for (int c = 0; c < 2; ++c)
        a2[c] = *(const short8*)(&outlds[wave][llo][c * 32 + lhi * 8]);
    #pragma unroll
    for (int o = 0; o < 15; ++o) {
        f32x4 hacc = (f32x4){0.f, 0.f, 0.f, 0.f};
        #pragma unroll
        for (int c = 0; c < 2; ++c) {
            short8 b = *(const short8*)(wcatT + (o * 16 + llo) * 64 + c * 32 + lhi * 8);
            hacc = __builtin_amdgcn_mfma_f32_16x16x32_bf16(a2[c], b, hacc, 0, 0, 0);
        }
        int col = o * 16 + llo;
        float bv; size_t off0; int w_, csh;
        if (col < 16)       { bv = bsup[col];       off0 = 0;                 w_ = 16;  csh = 0;   }
        else if (col < 48)  { bv = bnt[col - 16];   off0 = (size_t)NN * 16;   w_ = 32;  csh = 16;  }
        else if (col < 112) { bv = btg[col - 48];   off0 = (size_t)NN * 48;   w_ = 64;  csh = 48;  }
        else                { bv = bpr[col - 112];  off0 = (size_t)NN * 112;  w_ = 128; csh = 112; }
        #pragma unroll
        for (int r = 0; r < 4; ++r) {
            int node = n0 + lhi * 4 + r;
            if (live && node < NN)
                outp[off0 + (size_t)node * w_ + (col - csh)] = hacc[r] + bv;
        }
    }
}

extern "C" void kernel_launch(void* const* d_in, const int* in_sizes, int n_in,
                              void* d_out, int out_size, void* d_ws, size_t ws_size,
                              hipStream_t stream) {
    const float* x        = (const float*)d_in[0];
    const int* input_np   = (const int*)d_in[1];
    const int* output_np  = (const int*)d_in[2];
    const int* edge_idx   = (const int*)d_in[3];
    const int* edge_nt    = (const int*)d_in[4];
    const int* edge_np    = (const int*)d_in[5];
    const float* edge_sc  = (const float*)d_in[6];
    const float* in_emb   = (const float*)d_in[7];
    const float* out_emb  = (const float*)d_in[8];
    const float* enp_emb  = (const float*)d_in[9];
    const float* ent_emb  = (const float*)d_in[10];
    const float* w1       = (const float*)d_in[11];
    const float* b1       = (const float*)d_in[12];
    const float* w2       = (const float*)d_in[13];
    const float* b2       = (const float*)d_in[14];
    const float* rootw    = (const float*)d_in[15];
    const float* convb    = (const float*)d_in[16];
    const float* wsup     = (const float*)d_in[17];
    const float* bsup     = (const float*)d_in[18];
    const float* wnt      = (const float*)d_in[19];
    const float* bnt      = (const float*)d_in[20];
    const float* wtg      = (const float*)d_in[21];
    const float* btg      = (const float*)d_in[22];
    const float* wpr      = (const float*)d_in[23];
    const float* bpr      = (const float*)d_in[24];

    char* ws = (char*)d_ws;
    u16* xf    = (u16*)(ws + XF_OFF);
    u16* w2t   = (u16*)(ws + W2T_OFF);
    u16* rootT = (u16*)(ws + ROOTT_OFF);
    u16* wcatT = (u16*)(ws + WCATT_OFF);
    float* sums = (float*)(ws + SUMS_OFF);
    float* cnt  = sums + (size_t)NN * 64;
    u16* h2    = (u16*)(ws + H2_OFF);

    k_pre<<<3242, 256, 0, stream>>>(x, input_np, output_np, edge_nt, edge_np, edge_sc,
                                    in_emb, out_emb, ent_emb, enp_emb, w1, b1, w2, b2,
                                    rootw, wsup, wnt, wtg, wpr,
                                    xf, w2t, rootT, wcatT, h2, (float4*)sums);
    k_msg<<<512, 1024, 0, stream>>>(edge_idx, xf, h2, w2t, sums, cnt);
    k_out<<<235, 256, 0, stream>>>(xf, sums, cnt, rootT, wcatT, convb, bsup, bnt, btg, bpr, (float*)d_out);
}

// Round 22
// 81.958 us; speedup vs baseline: 1.1043x; 1.1043x over previous
//
#include <hip/hip_runtime.h>
#include <stdint.h>

#define NN 15000
#define NE 60000

typedef unsigned short u16;
typedef __attribute__((ext_vector_type(8))) short short8;
typedef __attribute__((ext_vector_type(4))) float f32x4;

// workspace layout (bytes)
#define XF_OFF    0u          // xf   : 15000*64*2 = 1,920,000
#define W2T_OFF   1920000u    // w2t  : 65*4096*2  =   532,480
#define ROOTT_OFF 2452480u    // rootT: 64*64*2    =     8,192
#define WCATT_OFF 2460672u    // wcatT: 240*64*2   =    30,720
#define SUMS_OFF  2491392u    // sums+cnt: 15000*65*4 = 3,900,000
#define H2_OFF    6391392u    // h2   : [e/4][64][4] = 60000*64*2 = 7,680,000 -> end 14,071,392

__device__ __forceinline__ unsigned cvtpk(float lo, float hi) {
    unsigned r;
    asm("v_cvt_pk_bf16_f32 %0, %1, %2" : "=v"(r) : "v"(lo), "v"(hi));
    return r;
}
__device__ __forceinline__ u16 f2b(float f) { return (u16)(cvtpk(f, f) & 0xffffu); }

// =============== K1: fused {h-MLP(MFMA)->h2, xf, weight-prep, zero} ===============
// block ranges: [0,938) h | [938,1876) xf | [1876,2992) prep | [2992,3945) zero
__global__ __launch_bounds__(256) void k_pre(
        const float* __restrict__ x,
        const int* __restrict__ inp, const int* __restrict__ outp,
        const int* __restrict__ ent, const int* __restrict__ enp,
        const float* __restrict__ esc,
        const float* __restrict__ in_emb, const float* __restrict__ out_emb,
        const float* __restrict__ nt_emb, const float* __restrict__ np_emb,
        const float* __restrict__ w1, const float* __restrict__ b1,
        const float* __restrict__ w2, const float* __restrict__ b2,
        const float* __restrict__ rootw,
        const float* __restrict__ wsup, const float* __restrict__ wnt,
        const float* __restrict__ wtg, const float* __restrict__ wpr,
        u16* __restrict__ xf, u16* __restrict__ w2t,
        u16* __restrict__ rootT, u16* __restrict__ wcatT,
        u16* __restrict__ h2, float4* __restrict__ zbase) {
    const int bid = blockIdx.x, tid = threadIdx.x;
    if (bid < 938) {
        // ---- h = relu(ea @ w1 + b1) via MFMA; output in h2 stream layout
        // h2[(e>>2)*256 + k*4 + (e&3)].
        __shared__ __align__(16) u16 w1t[64 * 64];   // [col][k], k 33..63 zero-padded
        __shared__ float b1s[64];
        const int lane = tid & 63, wave = tid >> 6;
        const int lhi = lane >> 4, llo = lane & 15;
        for (int idx = tid; idx < 4096; idx += 256) {
            int col = idx >> 6, k = idx & 63;
            w1t[col * 64 + k] = f2b((k < 33) ? w1[k * 64 + col] : 0.f);
        }
        if (tid < 64) b1s[tid] = b1[tid];
        __syncthreads();
        int g = bid * 4 + wave;                     // 16-edge group, 0..3751
        if (g >= 3750) return;                      // 60000/16 = 3750 exactly
        int e = g * 16 + llo;                       // A-frag row = edge
        short8 A0;
        {
            const float* src = (lhi < 2) ? (nt_emb + (size_t)ent[e] * 16 + lhi * 8)
                                         : (np_emb + (size_t)enp[e] * 16 + (lhi - 2) * 8);
            float4 v0 = *(const float4*)(src);
            float4 v1 = *(const float4*)(src + 4);
            union { short8 s; unsigned u[4]; } Au;
            Au.u[0] = cvtpk(v0.x, v0.y); Au.u[1] = cvtpk(v0.z, v0.w);
            Au.u[2] = cvtpk(v1.x, v1.y); Au.u[3] = cvtpk(v1.z, v1.w);
            A0 = Au.s;
        }
        short8 A1 = (short8){0, 0, 0, 0, 0, 0, 0, 0};
        if (lhi == 0) {
            union { short8 s; unsigned u[4]; } Au;
            Au.s = A1; Au.u[0] = cvtpk(esc[e], 0.f); A1 = Au.s;
        }
        #pragma unroll
        for (int o = 0; o < 4; ++o) {
            short8 B0 = *(const short8*)(&w1t[(o * 16 + llo) * 64 + lhi * 8]);
            short8 B1 = *(const short8*)(&w1t[(o * 16 + llo) * 64 + 32 + lhi * 8]);
            f32x4 q;
            q = __builtin_amdgcn_mfma_f32_16x16x32_bf16(A0, B0, (f32x4){0.f,0.f,0.f,0.f}, 0, 0, 0);
            q = __builtin_amdgcn_mfma_f32_16x16x32_bf16(A1, B1, q, 0, 0, 0);
            int kh = o * 16 + llo;                  // hidden unit (D col)
            float bv = b1s[kh];
            float v0 = fmaxf(q[0] + bv, 0.f), v1 = fmaxf(q[1] + bv, 0.f);
            float v2 = fmaxf(q[2] + bv, 0.f), v3 = fmaxf(q[3] + bv, 0.f);
            uint2 pk2 = make_uint2(cvtpk(v0, v1), cvtpk(v2, v3));
            *(uint2*)(h2 + (size_t)(g * 4 + lhi) * 256 + kh * 4) = pk2;
        }
    } else if (bid < 1876) {
        // ---- xf = bf16(concat(x, in_emb[inp], out_emb[outp])) ----
        int t = (bid - 938) * 256 + tid;
        if (t >= NN * 16) return;
        int n = t >> 4, j4 = t & 15;
        float4 v;
        if (j4 < 8)       v = *(const float4*)(x + n * 32 + j4 * 4);
        else if (j4 < 12) v = *(const float4*)(in_emb + inp[n] * 16 + (j4 - 8) * 4);
        else              v = *(const float4*)(out_emb + outp[n] * 16 + (j4 - 12) * 4);
        uint2 p;
        p.x = cvtpk(v.x, v.y);
        p.y = cvtpk(v.z, v.w);
        *(uint2*)(xf + n * 64 + j4 * 4) = p;
    } else if (bid < 2992) {
        // ---- weight re-layouts ----
        int idx = (bid - 1876) * 256 + tid;
        if (idx < 65 * 4096) {
            int k = idx >> 12, r = idx & 4095, o = r >> 6, i = r & 63;
            float v = (k < 64) ? w2[(k << 12) + (i << 6) + o] : b2[(i << 6) + o];
            w2t[idx] = f2b(v);
        } else if (idx < 65 * 4096 + 4096) {
            int t = idx - 65 * 4096; int c = t >> 6, i = t & 63;
            rootT[t] = f2b(rootw[i * 64 + c]);
        } else if (idx < 65 * 4096 + 4096 + 15360) {
            int t = idx - (65 * 4096 + 4096); int col = t >> 6, k = t & 63;
            float v;
            if (col < 16)       v = wsup[k * 16 + col];
            else if (col < 48)  v = wnt[k * 32 + col - 16];
            else if (col < 112) v = wtg[k * 64 + col - 48];
            else                v = wpr[k * 128 + col - 112];
            wcatT[t] = f2b(v);
        }
    } else {
        // ---- zero sums+cnt ----
        int i = (bid - 2992) * 256 + tid;
        if (i < (NN * 65) / 4) zbase[i] = make_float4(0.f, 0.f, 0.f, 0.f);
    }
}

// =============== K2: fused msg GEMM + scatter-add (o-partitioned, 16-wave blocks) ===============
// msg[e,o] = sum_k h[e,k]*q_k[e,o] + bias,  q_k[e,o] = sum_i g[e,i]*w2t[k][o][i]
// grid 256; block = 1024 thr = 16 waves + 130KB LDS -> one workgroup/CU, 4 waves/SIMD.
// BEST MEASURED CONFIG (round-19 bench: k_msg 48.6us, VGPR 52, FETCH 9MB, 0 conflicts):
// - 32-edge wave tile: the only design whose loop state (~52 regs) fits the immovable
//   64-VGPR cap for 1024-thr blocks (rounds 14/15: three knobs failed to raise it).
// - XCD-local swizzle (oq=(bid>>3)&3, chunk=(bid&7)*8+(bid>>5)): h2 fetched once per XCD,
//   L2-resident (round 18: FETCH 29->12MB).
// - Loop `unroll 1` (round-10 full-unroll spill storm); atomics once per (edge,col).
// Falsified alternatives: setprio (round 20, -0.8us), k-split 2 blocks/CU (rounds 12/21,
// +8us: occupancy gain < duplicated-work cost), ping-pong prefetch (round 16, spill storm).
__global__ __launch_bounds__(1024)
void k_msg(const int* __restrict__ ei,
           const u16* __restrict__ xf,
           const u16* __restrict__ h2,
           const u16* __restrict__ w2t,
           float* __restrict__ sums,
           float* __restrict__ cnt) {
    __shared__ __align__(16) char smem[65 * 2048];   // 133,120 B
    const int tid  = threadIdx.x;
    const int lane = tid & 63;
    const int wave = tid >> 6;                       // 0..15
    const int lhi  = lane >> 4;
    const int llo  = lane & 15;
    const int bid  = blockIdx.x;
    const int oq    = (bid >> 3) & 3;                // 16-col quarter (XCD-local swizzle)
    const int chunk = (bid & 7) * 8 + (bid >> 5);    // 0..63 tile chunk
    const int wslot = chunk * 16 + wave;             // 0..1023 per oq

    // ---- one-time LDS fill: this oq's 2KB portion of each of the 65 slices ----
    for (int sl = wave; sl < 65; sl += 16) {
        const char* src = (const char*)w2t + (size_t)sl * 8192 + oq * 2048;
        char* dst = smem + sl * 2048;
        #pragma unroll
        for (int it = 0; it < 2; ++it) {
            int lin = (lane + it * 64) * 16;
            int phys = lin ^ (((lin >> 7) & 7) << 4);
            *(uint4*)(dst + phys) = *(const uint4*)(src + lin);
        }
    }
    __syncthreads();   // only barrier in the kernel

    const int pc0 = (llo * 128 + lhi * 16) ^ ((llo & 7) << 4);
    const int pc1 = (llo * 128 + 64 + lhi * 16) ^ ((llo & 7) << 4);

    for (int t = wslot; t < 1875; t += 1024) {       // 32-edge tiles; 1875*32 = 60000 exactly
        const int base = t * 32;
        short8 a[2][2]; int eb[2];
        #pragma unroll
        for (int st = 0; st < 2; ++st) {
            int e = base + st * 16 + llo;
            int src = ei[e];
            a[st][0] = *(const short8*)(xf + (size_t)src * 64 + lhi * 8);
            a[st][1] = *(const short8*)(xf + (size_t)src * 64 + 32 + lhi * 8);
            eb[st] = base + st * 16 + lhi * 4;
        }
        f32x4 acc[2];
        acc[0] = (f32x4){0.f, 0.f, 0.f, 0.f};
        acc[1] = (f32x4){0.f, 0.f, 0.f, 0.f};

        #pragma unroll 1   // CRITICAL: full unroll caused the round-9/10 spill storm
        for (int s = 0; s < 64; s += 2) {
            // h chunk: uint4 = slices {s,s+1} x this lane's 4 edges (L2-resident after swizzle)
            uint4 hc0 = *(const uint4*)(h2 + ((size_t)(eb[0] >> 2) << 8) + s * 4);
            uint4 hc1 = *(const uint4*)(h2 + ((size_t)(eb[1] >> 2) << 8) + s * 4);
            {   // slice s (h in hc*.x/.y)
                const char* bb = smem + s * 2048;
                short8 B0 = *(const short8*)(bb + pc0);
                short8 B1 = *(const short8*)(bb + pc1);
                f32x4 q0, q1;
                q0 = __builtin_amdgcn_mfma_f32_16x16x32_bf16(a[0][0], B0, (f32x4){0.f,0.f,0.f,0.f}, 0, 0, 0);
                q0 = __builtin_amdgcn_mfma_f32_16x16x32_bf16(a[0][1], B1, q0, 0, 0, 0);
                q1 = __builtin_amdgcn_mfma_f32_16x16x32_bf16(a[1][0], B0, (f32x4){0.f,0.f,0.f,0.f}, 0, 0, 0);
                q1 = __builtin_amdgcn_mfma_f32_16x16x32_bf16(a[1][1], B1, q1, 0, 0, 0);
                union { unsigned u; float f; } u0, u1, u2, u3;
                u0.u = hc0.x << 16;         u1.u = hc0.x & 0xffff0000u;
                u2.u = hc0.y << 16;         u3.u = hc0.y & 0xffff0000u;
                acc[0][0] = fmaf(u0.f, q0[0], acc[0][0]);
                acc[0][1] = fmaf(u1.f, q0[1], acc[0][1]);
                acc[0][2] = fmaf(u2.f, q0[2], acc[0][2]);
                acc[0][3] = fmaf(u3.f, q0[3], acc[0][3]);
                u0.u = hc1.x << 16;         u1.u = hc1.x & 0xffff0000u;
                u2.u = hc1.y << 16;         u3.u = hc1.y & 0xffff0000u;
                acc[1][0] = fmaf(u0.f, q1[0], acc[1][0]);
                acc[1][1] = fmaf(u1.f, q1[1], acc[1][1]);
                acc[1][2] = fmaf(u2.f, q1[2], acc[1][2]);
                acc[1][3] = fmaf(u3.f, q1[3], acc[1][3]);
            }
            {   // slice s+1 (h in hc*.z/.w)
                const char* bb = smem + (s + 1) * 2048;
                short8 B0 = *(const short8*)(bb + pc0);
                short8 B1 = *(const short8*)(bb + pc1);
                f32x4 q0, q1;
                q0 = __builtin_amdgcn_mfma_f32_16x16x32_bf16(a[0][0], B0, (f32x4){0.f,0.f,0.f,0.f}, 0, 0, 0);
                q0 = __builtin_amdgcn_mfma_f32_16x16x32_bf16(a[0][1], B1, q0, 0, 0, 0);
                q1 = __builtin_amdgcn_mfma_f32_16x16x32_bf16(a[1][0], B0, (f32x4){0.f,0.f,0.f,0.f}, 0, 0, 0);
                q1 = __builtin_amdgcn_mfma_f32_16x16x32_bf16(a[1][1], B1, q1, 0, 0, 0);
                union { unsigned u; float f; } u0, u1, u2, u3;
                u0.u = hc0.z << 16;         u1.u = hc0.z & 0xffff0000u;
                u2.u = hc0.w << 16;         u3.u = hc0.w & 0xffff0000u;
                acc[0][0] = fmaf(u0.f, q0[0], acc[0][0]);
                acc[0][1] = fmaf(u1.f, q0[1], acc[0][1]);
                acc[0][2] = fmaf(u2.f, q0[2], acc[0][2]);
                acc[0][3] = fmaf(u3.f, q0[3], acc[0][3]);
                u0.u = hc1.z << 16;         u1.u = hc1.z & 0xffff0000u;
                u2.u = hc1.w << 16;         u3.u = hc1.w & 0xffff0000u;
                acc[1][0] = fmaf(u0.f, q1[0], acc[1][0]);
                acc[1][1] = fmaf(u1.f, q1[1], acc[1][1]);
                acc[1][2] = fmaf(u2.f, q1[2], acc[1][2]);
                acc[1][3] = fmaf(u3.f, q1[3], acc[1][3]);
            }
        }
        {   // bias slice (LDS idx 64, h==1): MFMA straight into acc
            const char* bb = smem + 64 * 2048;
            short8 B0 = *(const short8*)(bb + pc0);
            short8 B1 = *(const short8*)(bb + pc1);
            #pragma unroll
            for (int st = 0; st < 2; ++st) {
                acc[st] = __builtin_amdgcn_mfma_f32_16x16x32_bf16(a[st][0], B0, acc[st], 0, 0, 0);
                acc[st] = __builtin_amdgcn_mfma_f32_16x16x32_bf16(a[st][1], B1, acc[st], 0, 0, 0);
            }
        }
        // scatter-add (C/D layout: col = oq*16+llo, row = lhi*4+r); oq0 also counts in-degree.
        #pragma unroll
        for (int st = 0; st < 2; ++st) {
            int4 d4 = *(const int4*)(ei + NE + eb[st]);
            #pragma unroll
            for (int r = 0; r < 4; ++r) {
                int d = (r == 0) ? d4.x : (r == 1) ? d4.y : (r == 2) ? d4.z : d4.w;
                atomicAdd(sums + (size_t)d * 64 + oq * 16 + llo, acc[st][r]);
                if (oq == 0 && llo == 0) atomicAdd(cnt + d, 1.0f);
            }
        }
    }
}

// =============== K3: out = relu(aggr + xf@rootw + b); 4 heads (f32 out) ===============
__global__ __launch_bounds__(256) void k_out(const u16* __restrict__ xf,
                                             const float* __restrict__ sums,
                                             const float* __restrict__ cnt,
                                             const u16* __restrict__ rootT,
                                             const u16* __restrict__ wcatT,
                                             const float* __restrict__ convb,
                                             const float* __restrict__ bsup,
                                             const float* __restrict__ bnt,
                                             const float* __restrict__ btg,
                                             const float* __restrict__ bpr,
                                             float* __restrict__ outp) {
    __shared__ __align__(16) u16 outlds[4][16][72];
    int tid = threadIdx.x;
    int wave = tid >> 6, lane = tid & 63;
    int lhi = lane >> 4, llo = lane & 15;
    int sid = blockIdx.x * 4 + wave;
    const bool live = (sid < 938);
    if (!live) sid = 937;
    int n0 = sid * 16;

    short8 a1[2];
    #pragma unroll
    for (int c = 0; c < 2; ++c) {
        int node = n0 + llo; if (node >= NN) node = NN - 1;
        a1[c] = *(const short8*)(xf + (size_t)node * 64 + c * 32 + lhi * 8);
    }
    f32x4 racc[4];
    #pragma unroll
    for (int o = 0; o < 4; ++o) racc[o] = (f32x4){0.f, 0.f, 0.f, 0.f};
    #pragma unroll
    for (int c = 0; c < 2; ++c)
        #pragma unroll
        for (int o = 0; o < 4; ++o) {
            short8 b = *(const short8*)(rootT + (o * 16 + llo) * 64 + c * 32 + lhi * 8);
            racc[o] = __builtin_amdgcn_mfma_f32_16x16x32_bf16(a1[c], b, racc[o], 0, 0, 0);
        }
    #pragma unroll
    for (int o = 0; o < 4; ++o) {
        int col = o * 16 + llo;
        #pragma unroll
        for (int r = 0; r < 4; ++r) {
            int node = n0 + lhi * 4 + r;
            float v = 0.f;
            if (node < NN) v = sums[(size_t)node * 64 + col] / fmaxf(cnt[node], 1.0f);
            v += racc[o][r] + convb[col];
            v = fmaxf(v, 0.f);
            outlds[wave][lhi * 4 + r][col] = f2b(v);
        }
    }
    __syncthreads();
    short8 a2[2];
    #pragma unroll
    for (int c = 0; c < 2; ++c)
        a2[c] = *(const short8*)(&outlds[wave][llo][c * 32 + lhi * 8]);
    #pragma unroll
    for (int o = 0; o < 15; ++o) {
        f32x4 hacc = (f32x4){0.f, 0.f, 0.f, 0.f};
        #pragma unroll
        for (int c = 0; c < 2; ++c) {
            short8 b = *(const short8*)(wcatT + (o * 16 + llo) * 64 + c * 32 + lhi * 8);
            hacc = __builtin_amdgcn_mfma_f32_16x16x32_bf16(a2[c], b, hacc, 0, 0, 0);
        }
        int col = o * 16 + llo;
        float bv; size_t off0; int w_, csh;
        if (col < 16)       { bv = bsup[col];       off0 = 0;                 w_ = 16;  csh = 0;   }
        else if (col < 48)  { bv = bnt[col - 16];   off0 = (size_t)NN * 16;   w_ = 32;  csh = 16;  }
        else if (col < 112) { bv = btg[col - 48];   off0 = (size_t)NN * 48;   w_ = 64;  csh = 48;  }
        else                { bv = bpr[col - 112];  off0 = (size_t)NN * 112;  w_ = 128; csh = 112; }
        #pragma unroll
        for (int r = 0; r < 4; ++r) {
            int node = n0 + lhi * 4 + r;
            if (live && node < NN)
                outp[off0 + (size_t)node * w_ + (col - csh)] = hacc[r] + bv;
        }
    }
}

extern "C" void kernel_launch(void* const* d_in, const int* in_sizes, int n_in,
                              void* d_out, int out_size, void* d_ws, size_t ws_size,
                              hipStream_t stream) {
    const float* x        = (const float*)d_in[0];
    const int* input_np   = (const int*)d_in[1];
    const int* output_np  = (const int*)d_in[2];
    const int* edge_idx   = (const int*)d_in[3];
    const int* edge_nt    = (const int*)d_in[4];
    const int* edge_np    = (const int*)d_in[5];
    const float* edge_sc  = (const float*)d_in[6];
    const float* in_emb   = (const float*)d_in[7];
    const float* out_emb  = (const float*)d_in[8];
    const float* enp_emb  = (const float*)d_in[9];
    const float* ent_emb  = (const float*)d_in[10];
    const float* w1       = (const float*)d_in[11];
    const float* b1       = (const float*)d_in[12];
    const float* w2       = (const float*)d_in[13];
    const float* b2       = (const float*)d_in[14];
    const float* rootw    = (const float*)d_in[15];
    const float* convb    = (const float*)d_in[16];
    const float* wsup     = (const float*)d_in[17];
    const float* bsup     = (const float*)d_in[18];
    const float* wnt      = (const float*)d_in[19];
    const float* bnt      = (const float*)d_in[20];
    const float* wtg      = (const float*)d_in[21];
    const float* btg      = (const float*)d_in[22];
    const float* wpr      = (const float*)d_in[23];
    const float* bpr      = (const float*)d_in[24];

    char* ws = (char*)d_ws;
    u16* xf    = (u16*)(ws + XF_OFF);
    u16* w2t   = (u16*)(ws + W2T_OFF);
    u16* rootT = (u16*)(ws + ROOTT_OFF);
    u16* wcatT = (u16*)(ws + WCATT_OFF);
    float* sums = (float*)(ws + SUMS_OFF);
    float* cnt  = sums + (size_t)NN * 64;
    u16* h2    = (u16*)(ws + H2_OFF);

    k_pre<<<3945, 256, 0, stream>>>(x, input_np, output_np, edge_nt, edge_np, edge_sc,
                                    in_emb, out_emb, ent_emb, enp_emb, w1, b1, w2, b2,
                                    rootw, wsup, wnt, wtg, wpr,
                                    xf, w2t, rootT, wcatT, h2, (float4*)sums);
    k_msg<<<256, 1024, 0, stream>>>(edge_idx, xf, h2, w2t, sums, cnt);
    k_out<<<235, 256, 0, stream>>>(xf, sums, cnt, rootT, wcatT, convb, bsup, bnt, btg, bpr, (float*)d_out);
}